// Round 1
// baseline (356.176 us; speedup 1.0000x reference)
//
#include <hip/hip_runtime.h>
#include <hip/hip_bf16.h>

#define NEG_INF -1e20f

typedef __bf16 bf16x8 __attribute__((ext_vector_type(8)));
typedef float  f32x4  __attribute__((ext_vector_type(4)));

__device__ inline unsigned short f2bf(float x) {            // RNE, no NaN inputs
    unsigned u = __float_as_uint(x);
    unsigned r = u + 0x7fffu + ((u >> 16) & 1u);
    return (unsigned short)(r >> 16);
}
__device__ inline float bf2f(unsigned short h) {
    return __uint_as_float((unsigned)h << 16);
}
__device__ inline unsigned fkey(float f) {
    unsigned u = __float_as_uint(f);
    return (u & 0x80000000u) ? ~u : (u | 0x80000000u);
}
__device__ inline float unfkey(unsigned k) {
    unsigned fu = (k & 0x80000000u) ? (k ^ 0x80000000u) : ~k;
    return __uint_as_float(fu);
}

// ---------------------------------------------------------------------------
// K0: split ctx AND W into 3 bf16 planes each, one launch. VERBATIM.
// ---------------------------------------------------------------------------
__global__ __launch_bounds__(256) void split3_all(
        const float* __restrict__ ctx, const float* __restrict__ W,
        unsigned short* __restrict__ C1, unsigned short* __restrict__ C2,
        unsigned short* __restrict__ C3, unsigned short* __restrict__ W1,
        unsigned short* __restrict__ W2, unsigned short* __restrict__ W3) {
    const int b = blockIdx.x;
    const int t = threadIdx.x;
    const float* src;
    unsigned short *p1, *p2, *p3;
    int base;
    if (b < 2048) { src = ctx; p1 = C1; p2 = C2; p3 = C3; base = b * 1024; }
    else          { src = W;   p1 = W1; p2 = W2; p3 = W3; base = (b - 2048) * 1024; }
#pragma unroll
    for (int it = 0; it < 4; ++it) {
        int i = base + it * 256 + t;
        float4 v = ((const float4*)src)[i];
        ushort4 a, bb, c;
        float r;
        a.x = f2bf(v.x); r = v.x - bf2f(a.x); bb.x = f2bf(r); c.x = f2bf(r - bf2f(bb.x));
        a.y = f2bf(v.y); r = v.y - bf2f(a.y); bb.y = f2bf(r); c.y = f2bf(r - bf2f(bb.y));
        a.z = f2bf(v.z); r = v.z - bf2f(a.z); bb.z = f2bf(r); c.z = f2bf(r - bf2f(bb.z));
        a.w = f2bf(v.w); r = v.w - bf2f(a.w); bb.w = f2bf(r); c.w = f2bf(r - bf2f(bb.w));
        ((ushort4*)p1)[i] = a;
        ((ushort4*)p2)[i] = bb;
        ((ushort4*)p3)[i] = c;
    }
}

// ---------------------------------------------------------------------------
// K1: ctx_fc = relu(context @ W^T) via 6-term bf16 MFMA, 128x128 tile. VERBATIM.
// ---------------------------------------------------------------------------
__global__ __launch_bounds__(256, 2) void fc_mfma6(
        const unsigned short* __restrict__ A1, const unsigned short* __restrict__ A2,
        const unsigned short* __restrict__ A3, const unsigned short* __restrict__ B1,
        const unsigned short* __restrict__ B2, const unsigned short* __restrict__ B3,
        unsigned short* __restrict__ Fhi, unsigned short* __restrict__ Flo) {
    __shared__ char lds[49152];

    const int t     = threadIdx.x;
    const int mBase = blockIdx.x * 128;
    const int hBase = blockIdx.y * 128;
    const int w = t >> 6, lane = t & 63;
    const int q = lane >> 4, ln = lane & 15;
    const int wn = (w >> 1) * 64;
    const int wm = (w & 1) * 64;

    f32x4 acc[4][4] = {};

    for (int kt = 0; kt < 512; kt += 32) {
#pragma unroll
        for (int p = 0; p < 3; ++p) {
            const unsigned short* pl = (p == 0) ? A1 : (p == 1) ? A2 : A3;
#pragma unroll
            for (int rr = 0; rr < 2; ++rr) {
                int chunk = rr * 256 + t;
                int row   = chunk >> 2;
                int c     = (chunk & 3) ^ ((row >> 1) & 3);
                const unsigned short* g = pl + ((size_t)(mBase + row) * 512 + kt + c * 8);
                char* l = lds + p * 8192 + chunk * 16;
                __builtin_amdgcn_global_load_lds(
                    (const __attribute__((address_space(1))) void*)g,
                    (__attribute__((address_space(3))) void*)l, 16, 0, 0);
            }
        }
#pragma unroll
        for (int p = 0; p < 3; ++p) {
            const unsigned short* pl = (p == 0) ? B1 : (p == 1) ? B2 : B3;
#pragma unroll
            for (int rr = 0; rr < 2; ++rr) {
                int chunk = rr * 256 + t;
                int row   = chunk >> 2;
                int c     = (chunk & 3) ^ ((row >> 1) & 3);
                const unsigned short* g = pl + ((size_t)(hBase + row) * 512 + kt + c * 8);
                char* l = lds + 24576 + p * 8192 + chunk * 16;
                __builtin_amdgcn_global_load_lds(
                    (const __attribute__((address_space(1))) void*)g,
                    (__attribute__((address_space(3))) void*)l, 16, 0, 0);
            }
        }
        __syncthreads();

        bf16x8 a1[4], a2[4], a3[4], b1[4], b2[4], b3[4];
#pragma unroll
        for (int i = 0; i < 4; ++i) {
            int mA = wn + i * 16 + ln;
            int oA = (mA * 4 + (q ^ ((mA >> 1) & 3))) * 16;
            a1[i] = *(const bf16x8*)(lds +     0 + oA);
            a2[i] = *(const bf16x8*)(lds +  8192 + oA);
            a3[i] = *(const bf16x8*)(lds + 16384 + oA);
            int mB = wm + i * 16 + ln;
            int oB = (mB * 4 + (q ^ ((mB >> 1) & 3))) * 16;
            b1[i] = *(const bf16x8*)(lds + 24576 + oB);
            b2[i] = *(const bf16x8*)(lds + 32768 + oB);
            b3[i] = *(const bf16x8*)(lds + 40960 + oB);
        }
#pragma unroll
        for (int i = 0; i < 4; ++i)
#pragma unroll
            for (int j = 0; j < 4; ++j) {
                acc[i][j] = __builtin_amdgcn_mfma_f32_16x16x32_bf16(a1[i], b1[j], acc[i][j], 0, 0, 0);
                acc[i][j] = __builtin_amdgcn_mfma_f32_16x16x32_bf16(a1[i], b2[j], acc[i][j], 0, 0, 0);
                acc[i][j] = __builtin_amdgcn_mfma_f32_16x16x32_bf16(a2[i], b1[j], acc[i][j], 0, 0, 0);
                acc[i][j] = __builtin_amdgcn_mfma_f32_16x16x32_bf16(a2[i], b2[j], acc[i][j], 0, 0, 0);
                acc[i][j] = __builtin_amdgcn_mfma_f32_16x16x32_bf16(a1[i], b3[j], acc[i][j], 0, 0, 0);
                acc[i][j] = __builtin_amdgcn_mfma_f32_16x16x32_bf16(a3[i], b1[j], acc[i][j], 0, 0, 0);
            }
        __syncthreads();
    }

    unsigned* tb = (unsigned*)(lds + w * 4352);
    const int rg = lane >> 4;
    const int c4 = lane & 15;
#pragma unroll
    for (int i = 0; i < 4; ++i) {
#pragma unroll
        for (int j = 0; j < 4; ++j)
#pragma unroll
            for (int r = 0; r < 4; ++r) {
                float v = fmaxf(acc[i][j][r], 0.f);
                unsigned short hi = f2bf(v);
                unsigned short lo = f2bf(v - bf2f(hi));
                tb[(q * 4 + r) * 68 + j * 16 + ln] =
                    (unsigned)hi | ((unsigned)lo << 16);
            }
#pragma unroll
        for (int it = 0; it < 4; ++it) {
            int row = it * 4 + rg;
            uint4 pk = *(const uint4*)&tb[row * 68 + c4 * 4];
            ushort4 h, l;
            h.x = (unsigned short)pk.x; l.x = (unsigned short)(pk.x >> 16);
            h.y = (unsigned short)pk.y; l.y = (unsigned short)(pk.y >> 16);
            h.z = (unsigned short)pk.z; l.z = (unsigned short)(pk.z >> 16);
            h.w = (unsigned short)pk.w; l.w = (unsigned short)(pk.w >> 16);
            size_t off = (size_t)(mBase + wn + i * 16 + row) * 512 + hBase + wm + c4 * 4;
            *(ushort4*)(Fhi + off) = h;
            *(ushort4*)(Flo + off) = l;
        }
    }
}

// ---------------------------------------------------------------------------
// select10: exact top-10 of one 128-value row held in LDS, by an 8-lane group.
// prow = &patch[pr*132 + g*16]. Returns fkey+localcol candidates:
// c0 for rounds 0..7 (lane g==r), c1 for rounds 8..9 (lane g==r-8).
// topk_rows' proven pattern: local top-2 + iterative group argmax + rescan.
// ---------------------------------------------------------------------------
__device__ __forceinline__ void select10(const float* prow, int g,
        unsigned& c0k, int& c0c, unsigned& c1k, int& c1c) {
    unsigned k[16];
#pragma unroll
    for (int s = 0; s < 4; ++s) {
        float4 v = *(const float4*)(prow + s * 4);
        k[s*4+0] = fkey(v.x); k[s*4+1] = fkey(v.y);
        k[s*4+2] = fkey(v.z); k[s*4+3] = fkey(v.w);
    }
    unsigned h1 = k[0]; int i1 = 0;
#pragma unroll
    for (int j = 1; j < 16; ++j) if (k[j] > h1) { h1 = k[j]; i1 = j; }
    unsigned h2 = 0; int i2 = 0;
#pragma unroll
    for (int j = 0; j < 16; ++j) { bool ok = (j != i1) && (k[j] > h2); h2 = ok ? k[j] : h2; i2 = ok ? j : i2; }
    bool h2v = true; unsigned taken = 0;
    c0k = 0; c0c = 0; c1k = 0; c1c = 0;
#pragma unroll
    for (int r = 0; r < 10; ++r) {
        unsigned long long P = ((unsigned long long)h1 << 32) | (unsigned)(g * 16 + i1);
#pragma unroll
        for (int off = 1; off < 8; off <<= 1) {
            unsigned long long Q = __shfl_xor(P, off, 64);
            P = (Q > P) ? Q : P;
        }
        unsigned M = (unsigned)(P >> 32);
        int cl = (int)(P & 0xffffu);
        if (r < 8) { if (g == r)     { c0k = M; c0c = cl; } }
        else       { if (g == r - 8) { c1k = M; c1c = cl; } }
        if ((cl >> 4) == g) {                       // I own the winner: pop it
            taken |= 1u << (cl & 15);
            if (h2v) { h1 = h2; i1 = i2; h2v = false; }
            else {
                unsigned bh = 0; int bi = 0;
#pragma unroll
                for (int jx = 0; jx < 16; ++jx) {
                    bool ok = (((taken >> jx) & 1u) == 0u) && (k[jx] > bh);
                    bh = ok ? k[jx] : bh; bi = ok ? jx : bi;
                }
                h1 = bh; i1 = bi;
            }
        }
    }
}

// ---------------------------------------------------------------------------
// K2: att = F F^T, SYMMETRIC 136 upper-triangle pairs — K-loop VERBATIM.
// NEW epilogue: NO matrix write. Instead emits exact per-tile per-row top-10
// candidates (f32 value + u16 global col) for BOTH the row panel (slot tj)
// and, if off-diagonal, the mirror col panel (slot ti). 8 LDS [32][132]
// staging+selection passes replace the old transpose+store epilogue.
// ---------------------------------------------------------------------------
__global__ __launch_bounds__(256, 2) void att_cand(
        const unsigned short* __restrict__ Fhi, const unsigned short* __restrict__ Flo,
        const int* __restrict__ mask, float* __restrict__ cvO,
        unsigned short* __restrict__ ciO) {
    __shared__ char lds[32768];

    const int t = threadIdx.x;
    const int b = blockIdx.x & 7;        // XCD-pinned batch
    int p = blockIdx.x >> 3, ti = 0;     // pair 0..135
    while (p >= 16 - ti) { p -= 16 - ti; ++ti; }
    const int tj = ti + p;
    const int nBase = ti * 128;
    const int mBase = tj * 128;
    const int w    = t >> 6, lane = t & 63;
    const int q    = lane >> 4, ln = lane & 15;
    const int wn   = (w >> 1) * 64;
    const int wm   = (w & 1) * 64;
    const size_t rowB = (size_t)b * 2048;

    f32x4 acc[4][4] = {};

    for (int kt = 0; kt < 512; kt += 32) {
#pragma unroll
        for (int pp = 0; pp < 4; ++pp) {
            const unsigned short* plane = (pp & 1) ? Flo : Fhi;
            int rbase = (pp < 2) ? nBase : mBase;
#pragma unroll
            for (int r = 0; r < 2; ++r) {
                int chunk = r * 256 + t;
                int row   = chunk >> 2;
                int c     = (chunk & 3) ^ ((row >> 1) & 3);
                const unsigned short* g =
                    plane + ((rowB + rbase + row) * 512 + kt + c * 8);
                char* l = lds + pp * 8192 + chunk * 16;
                __builtin_amdgcn_global_load_lds(
                    (const __attribute__((address_space(1))) void*)g,
                    (__attribute__((address_space(3))) void*)l, 16, 0, 0);
            }
        }
        __syncthreads();

        bf16x8 ah[4], al[4], bh[4], bl[4];
#pragma unroll
        for (int i = 0; i < 4; ++i) {
            int mA = wn + i * 16 + ln;
            int oA = (mA * 4 + (q ^ ((mA >> 1) & 3))) * 16;
            ah[i] = *(const bf16x8*)(lds +     0 + oA);
            al[i] = *(const bf16x8*)(lds +  8192 + oA);
            int mB = wm + i * 16 + ln;
            int oB = (mB * 4 + (q ^ ((mB >> 1) & 3))) * 16;
            bh[i] = *(const bf16x8*)(lds + 16384 + oB);
            bl[i] = *(const bf16x8*)(lds + 24576 + oB);
        }
#pragma unroll
        for (int i = 0; i < 4; ++i)
#pragma unroll
            for (int j = 0; j < 4; ++j) {
                acc[i][j] = __builtin_amdgcn_mfma_f32_16x16x32_bf16(ah[i], bh[j], acc[i][j], 0, 0, 0);
                acc[i][j] = __builtin_amdgcn_mfma_f32_16x16x32_bf16(ah[i], bl[j], acc[i][j], 0, 0, 0);
                acc[i][j] = __builtin_amdgcn_mfma_f32_16x16x32_bf16(al[i], bh[j], acc[i][j], 0, 0, 0);
            }
        __syncthreads();
    }

    // ---------------- candidate-extraction epilogue ----------------
    float* patch = (float*)lds;               // [32][132] f32 = 16.9 KB
    const int* mb = mask + b * 2048;

    int cmj[4];
#pragma unroll
    for (int j = 0; j < 4; ++j) cmj[j] = mb[mBase + wm + j * 16 + ln];
    int rmAll[4][4];
#pragma unroll
    for (int i = 0; i < 4; ++i)
#pragma unroll
        for (int r = 0; r < 4; ++r) rmAll[i][r] = mb[nBase + wn + i * 16 + q * 4 + r];

    const int pr = t >> 3, g = t & 7;         // selection role: row pr, lane g

    // --- row passes: rows of panel ti vs cols of panel tj (slot tj) ---
#pragma unroll
    for (int i = 0; i < 4; ++i) {
        int prBase = (w >> 1) * 16;
#pragma unroll
        for (int j = 0; j < 4; ++j)
#pragma unroll
            for (int r = 0; r < 4; ++r) {
                float v = ((rmAll[i][r] != 0) & (cmj[j] != 0)) ? acc[i][j][r] : NEG_INF;
                patch[(prBase + q * 4 + r) * 132 + wm + j * 16 + ln] = v;
            }
        __syncthreads();
        {
            unsigned c0k, c1k; int c0c, c1c;
            select10(patch + pr * 132 + g * 16, g, c0k, c0c, c1k, c1c);
            int rowG = nBase + ((pr >> 4) << 6) + i * 16 + (pr & 15);
            size_t cb = (((size_t)b * 2048 + rowG) * 16 + tj) * 10;
            cvO[cb + g] = unfkey(c0k);
            ciO[cb + g] = (unsigned short)(mBase + c0c);
            if (g < 2) {
                cvO[cb + 8 + g] = unfkey(c1k);
                ciO[cb + 8 + g] = (unsigned short)(nBase == mBase ? mBase + c1c : mBase + c1c);
            }
        }
        __syncthreads();
    }

    // --- mirror col passes: rows of panel tj vs cols of panel ti (slot ti) ---
    if (ti != tj) {
#pragma unroll
        for (int c2 = 0; c2 < 4; ++c2) {
            if ((w & 1) == (c2 >> 1)) {       // this wave's col-half covers c2*32..+32
                int jb = (c2 & 1) * 2;
#pragma unroll
                for (int jj = 0; jj < 2; ++jj) {
                    int j = jb + jj;
#pragma unroll
                    for (int i2 = 0; i2 < 4; ++i2)
#pragma unroll
                        for (int r = 0; r < 4; ++r) {
                            float v = ((rmAll[i2][r] != 0) & (cmj[j] != 0)) ? acc[i2][j][r] : NEG_INF;
                            patch[(jj * 16 + ln) * 132 + wn + i2 * 16 + q * 4 + r] = v;
                        }
                }
            }
            __syncthreads();
            {
                unsigned c0k, c1k; int c0c, c1c;
                select10(patch + pr * 132 + g * 16, g, c0k, c0c, c1k, c1c);
                int rowG = mBase + c2 * 32 + pr;
                size_t cb = (((size_t)b * 2048 + rowG) * 16 + ti) * 10;
                cvO[cb + g] = unfkey(c0k);
                ciO[cb + g] = (unsigned short)(nBase + c0c);
                if (g < 2) {
                    cvO[cb + 8 + g] = unfkey(c1k);
                    ciO[cb + 8 + g] = (unsigned short)(nBase + c1c);
                }
            }
            __syncthreads();
        }
    }
}

// ---------------------------------------------------------------------------
// K3: merge 16x10 exact per-tile candidates per row -> global top-10,
// write NEG_INF-filled row + scatter. One wave per row, zero barriers.
// ---------------------------------------------------------------------------
__global__ __launch_bounds__(256) void topk_merge(
        const float* __restrict__ cv, const unsigned short* __restrict__ ci,
        float* __restrict__ out) {
    __shared__ float patch[4][2048];

    const int t = threadIdx.x, w = t >> 6, lane = t & 63;
    const size_t R = (size_t)blockIdx.x * 4 + w;      // global row 0..16383
    const float* v = cv + R * 160;
    const unsigned short* id = ci + R * 160;

    float v0 = v[lane], v1 = v[lane + 64];
    int   c0 = id[lane], c1 = id[lane + 64];
    float v2 = NEG_INF;  int c2 = 0;
    if (lane < 32) { v2 = v[lane + 128]; c2 = id[lane + 128]; }
    unsigned k0 = fkey(v0), k1 = fkey(v1), k2 = fkey(v2);

    unsigned h1 = k0; int i1 = 0;
    if (k1 > h1) { h1 = k1; i1 = 1; }
    if (k2 > h1) { h1 = k2; i1 = 2; }
    unsigned taken = 0;
    unsigned myk = 0; int mycol = 0;

    for (int r = 0; r < 10; ++r) {
        unsigned M = h1;
#pragma unroll
        for (int off = 1; off < 64; off <<= 1) {
            unsigned o = __shfl_xor(M, off, 64);
            M = (o > M) ? o : M;
        }
        unsigned long long ball = __ballot(h1 == M);
        int src = __ffsll(ball) - 1;
        int csel = (i1 == 0) ? c0 : ((i1 == 1) ? c1 : c2);
        int wcol = __shfl(csel, src, 64);
        if (lane == r) { myk = M; mycol = wcol; }
        if (lane == src) {
            taken |= 1u << i1;
            unsigned bh = 0; int bi = 0;
            if (!(taken & 1u))            { bh = k0; bi = 0; }
            if (!(taken & 2u) && k1 > bh) { bh = k1; bi = 1; }
            if (!(taken & 4u) && k2 > bh) { bh = k2; bi = 2; }
            h1 = bh; i1 = bi;
        }
    }

    float* pw = patch[w];
    float4 ninf4 = make_float4(NEG_INF, NEG_INF, NEG_INF, NEG_INF);
#pragma unroll
    for (int s = 0; s < 8; ++s) ((float4*)pw)[s * 64 + lane] = ninf4;
    if (lane < 10) pw[mycol] = unfkey(myk);
    float* row = out + R * 2048;
#pragma unroll
    for (int s = 0; s < 8; ++s)
        ((float4*)row)[s * 64 + lane] = ((float4*)pw)[s * 64 + lane];
}

// ---------------------------------------------------------------------------
extern "C" void kernel_launch(void* const* d_in, const int* in_sizes, int n_in,
                              void* d_out, int out_size, void* d_ws, size_t ws_size,
                              hipStream_t stream) {
    const float* ctx  = (const float*)d_in[0];   // [8, 2048, 512]
    const float* W    = (const float*)d_in[1];   // [512, 512]
    const int*   mask = (const int*)d_in[2];     // [8, 2048]
    float* out = (float*)d_out;                  // [8, 2048, 2048]

    const size_t CN = (size_t)16384 * 512;
    const size_t WN = (size_t)512 * 512;
    // split planes live in the (still-unwritten) 134 MB output buffer
    unsigned short* C1 = (unsigned short*)d_out;
    unsigned short* C2 = C1 + CN;
    unsigned short* C3 = C2 + CN;
    unsigned short* W1 = C3 + CN;
    unsigned short* W2 = W1 + WN;
    unsigned short* W3 = W2 + WN;                // ends at 51.9 MB
    // Fhi/Flo ALSO in d_out (planes are dead once fc has read them is NOT
    // needed -- region is disjoint: [51.9 MB, 85.5 MB) < 134 MB). This frees
    // d_ws for the candidate arrays (15.7 MB, within the known-safe budget).
    unsigned short* Fhi = W3 + WN;
    unsigned short* Flo = Fhi + CN;

    float* cv          = (float*)d_ws;                       // [8*2048][16][10] f32
    unsigned short* ci = (unsigned short*)(cv + (size_t)8 * 2048 * 160); // u16 cols

    dim3 blk(256);
    split3_all<<<dim3(2112), blk, 0, stream>>>(ctx, W, C1, C2, C3, W1, W2, W3);
    fc_mfma6<<<dim3(128, 4), blk, 0, stream>>>(C1, C2, C3, W1, W2, W3, Fhi, Flo);
    att_cand<<<dim3(1088), blk, 0, stream>>>(Fhi, Flo, mask, cv, ci);
    topk_merge<<<dim3(4096), blk, 0, stream>>>(cv, ci, out);
}

// Round 2
// 347.780 us; speedup vs baseline: 1.0241x; 1.0241x over previous
//
#include <hip/hip_runtime.h>
#include <hip/hip_bf16.h>

#define NEG_INF -1e20f

typedef __bf16 bf16x8 __attribute__((ext_vector_type(8)));
typedef float  f32x4  __attribute__((ext_vector_type(4)));

__device__ inline unsigned short f2bf(float x) {            // RNE, no NaN inputs
    unsigned u = __float_as_uint(x);
    unsigned r = u + 0x7fffu + ((u >> 16) & 1u);
    return (unsigned short)(r >> 16);
}
__device__ inline float bf2f(unsigned short h) {
    return __uint_as_float((unsigned)h << 16);
}
__device__ inline unsigned fkey(float f) {
    unsigned u = __float_as_uint(f);
    return (u & 0x80000000u) ? ~u : (u | 0x80000000u);
}
__device__ inline float unfkey(unsigned k) {
    unsigned fu = (k & 0x80000000u) ? (k ^ 0x80000000u) : ~k;
    return __uint_as_float(fu);
}

// ---------------------------------------------------------------------------
// K0: split ctx AND W into 3 bf16 planes each, one launch. VERBATIM.
// ---------------------------------------------------------------------------
__global__ __launch_bounds__(256) void split3_all(
        const float* __restrict__ ctx, const float* __restrict__ W,
        unsigned short* __restrict__ C1, unsigned short* __restrict__ C2,
        unsigned short* __restrict__ C3, unsigned short* __restrict__ W1,
        unsigned short* __restrict__ W2, unsigned short* __restrict__ W3) {
    const int b = blockIdx.x;
    const int t = threadIdx.x;
    const float* src;
    unsigned short *p1, *p2, *p3;
    int base;
    if (b < 2048) { src = ctx; p1 = C1; p2 = C2; p3 = C3; base = b * 1024; }
    else          { src = W;   p1 = W1; p2 = W2; p3 = W3; base = (b - 2048) * 1024; }
#pragma unroll
    for (int it = 0; it < 4; ++it) {
        int i = base + it * 256 + t;
        float4 v = ((const float4*)src)[i];
        ushort4 a, bb, c;
        float r;
        a.x = f2bf(v.x); r = v.x - bf2f(a.x); bb.x = f2bf(r); c.x = f2bf(r - bf2f(bb.x));
        a.y = f2bf(v.y); r = v.y - bf2f(a.y); bb.y = f2bf(r); c.y = f2bf(r - bf2f(bb.y));
        a.z = f2bf(v.z); r = v.z - bf2f(a.z); bb.z = f2bf(r); c.z = f2bf(r - bf2f(bb.z));
        a.w = f2bf(v.w); r = v.w - bf2f(a.w); bb.w = f2bf(r); c.w = f2bf(r - bf2f(bb.w));
        ((ushort4*)p1)[i] = a;
        ((ushort4*)p2)[i] = bb;
        ((ushort4*)p3)[i] = c;
    }
}

// ---------------------------------------------------------------------------
// K1: ctx_fc = relu(context @ W^T) via 6-term bf16 MFMA, 128x128 tile. VERBATIM.
// ---------------------------------------------------------------------------
__global__ __launch_bounds__(256, 2) void fc_mfma6(
        const unsigned short* __restrict__ A1, const unsigned short* __restrict__ A2,
        const unsigned short* __restrict__ A3, const unsigned short* __restrict__ B1,
        const unsigned short* __restrict__ B2, const unsigned short* __restrict__ B3,
        unsigned short* __restrict__ Fhi, unsigned short* __restrict__ Flo) {
    __shared__ char lds[49152];

    const int t     = threadIdx.x;
    const int mBase = blockIdx.x * 128;
    const int hBase = blockIdx.y * 128;
    const int w = t >> 6, lane = t & 63;
    const int q = lane >> 4, ln = lane & 15;
    const int wn = (w >> 1) * 64;
    const int wm = (w & 1) * 64;

    f32x4 acc[4][4] = {};

    for (int kt = 0; kt < 512; kt += 32) {
#pragma unroll
        for (int p = 0; p < 3; ++p) {
            const unsigned short* pl = (p == 0) ? A1 : (p == 1) ? A2 : A3;
#pragma unroll
            for (int rr = 0; rr < 2; ++rr) {
                int chunk = rr * 256 + t;
                int row   = chunk >> 2;
                int c     = (chunk & 3) ^ ((row >> 1) & 3);
                const unsigned short* g = pl + ((size_t)(mBase + row) * 512 + kt + c * 8);
                char* l = lds + p * 8192 + chunk * 16;
                __builtin_amdgcn_global_load_lds(
                    (const __attribute__((address_space(1))) void*)g,
                    (__attribute__((address_space(3))) void*)l, 16, 0, 0);
            }
        }
#pragma unroll
        for (int p = 0; p < 3; ++p) {
            const unsigned short* pl = (p == 0) ? B1 : (p == 1) ? B2 : B3;
#pragma unroll
            for (int rr = 0; rr < 2; ++rr) {
                int chunk = rr * 256 + t;
                int row   = chunk >> 2;
                int c     = (chunk & 3) ^ ((row >> 1) & 3);
                const unsigned short* g = pl + ((size_t)(hBase + row) * 512 + kt + c * 8);
                char* l = lds + 24576 + p * 8192 + chunk * 16;
                __builtin_amdgcn_global_load_lds(
                    (const __attribute__((address_space(1))) void*)g,
                    (__attribute__((address_space(3))) void*)l, 16, 0, 0);
            }
        }
        __syncthreads();

        bf16x8 a1[4], a2[4], a3[4], b1[4], b2[4], b3[4];
#pragma unroll
        for (int i = 0; i < 4; ++i) {
            int mA = wn + i * 16 + ln;
            int oA = (mA * 4 + (q ^ ((mA >> 1) & 3))) * 16;
            a1[i] = *(const bf16x8*)(lds +     0 + oA);
            a2[i] = *(const bf16x8*)(lds +  8192 + oA);
            a3[i] = *(const bf16x8*)(lds + 16384 + oA);
            int mB = wm + i * 16 + ln;
            int oB = (mB * 4 + (q ^ ((mB >> 1) & 3))) * 16;
            b1[i] = *(const bf16x8*)(lds + 24576 + oB);
            b2[i] = *(const bf16x8*)(lds + 32768 + oB);
            b3[i] = *(const bf16x8*)(lds + 40960 + oB);
        }
#pragma unroll
        for (int i = 0; i < 4; ++i)
#pragma unroll
            for (int j = 0; j < 4; ++j) {
                acc[i][j] = __builtin_amdgcn_mfma_f32_16x16x32_bf16(a1[i], b1[j], acc[i][j], 0, 0, 0);
                acc[i][j] = __builtin_amdgcn_mfma_f32_16x16x32_bf16(a1[i], b2[j], acc[i][j], 0, 0, 0);
                acc[i][j] = __builtin_amdgcn_mfma_f32_16x16x32_bf16(a2[i], b1[j], acc[i][j], 0, 0, 0);
                acc[i][j] = __builtin_amdgcn_mfma_f32_16x16x32_bf16(a2[i], b2[j], acc[i][j], 0, 0, 0);
                acc[i][j] = __builtin_amdgcn_mfma_f32_16x16x32_bf16(a1[i], b3[j], acc[i][j], 0, 0, 0);
                acc[i][j] = __builtin_amdgcn_mfma_f32_16x16x32_bf16(a3[i], b1[j], acc[i][j], 0, 0, 0);
            }
        __syncthreads();
    }

    unsigned* tb = (unsigned*)(lds + w * 4352);
    const int rg = lane >> 4;
    const int c4 = lane & 15;
#pragma unroll
    for (int i = 0; i < 4; ++i) {
#pragma unroll
        for (int j = 0; j < 4; ++j)
#pragma unroll
            for (int r = 0; r < 4; ++r) {
                float v = fmaxf(acc[i][j][r], 0.f);
                unsigned short hi = f2bf(v);
                unsigned short lo = f2bf(v - bf2f(hi));
                tb[(q * 4 + r) * 68 + j * 16 + ln] =
                    (unsigned)hi | ((unsigned)lo << 16);
            }
#pragma unroll
        for (int it = 0; it < 4; ++it) {
            int row = it * 4 + rg;
            uint4 pk = *(const uint4*)&tb[row * 68 + c4 * 4];
            ushort4 h, l;
            h.x = (unsigned short)pk.x; l.x = (unsigned short)(pk.x >> 16);
            h.y = (unsigned short)pk.y; l.y = (unsigned short)(pk.y >> 16);
            h.z = (unsigned short)pk.z; l.z = (unsigned short)(pk.z >> 16);
            h.w = (unsigned short)pk.w; l.w = (unsigned short)(pk.w >> 16);
            size_t off = (size_t)(mBase + wn + i * 16 + row) * 512 + hBase + wm + c4 * 4;
            *(ushort4*)(Fhi + off) = h;
            *(ushort4*)(Flo + off) = l;
        }
    }
}

// ---------------------------------------------------------------------------
// select10f: exact top-10 of one 128-value row held in LDS, by an 8-lane group.
// Float compares (no fkey/u64 packing), owner via wave-ballot byte, local
// top-2 backup + rescan. c0 for rounds 0..7 (lane g==r), c1 for rounds 8..9.
// ---------------------------------------------------------------------------
__device__ __forceinline__ void select10f(const float* prow, int lane,
        float& c0v, int& c0c, float& c1v, int& c1c) {
    const int g = lane & 7;
    float v[16];
#pragma unroll
    for (int s = 0; s < 4; ++s) {
        float4 t4 = *(const float4*)(prow + s * 4);
        v[s*4+0] = t4.x; v[s*4+1] = t4.y; v[s*4+2] = t4.z; v[s*4+3] = t4.w;
    }
    float h1 = v[0]; int i1 = 0;
#pragma unroll
    for (int j = 1; j < 16; ++j) { bool c = v[j] > h1; h1 = c ? v[j] : h1; i1 = c ? j : i1; }
    float h2 = -3e38f; int i2 = 0;
#pragma unroll
    for (int j = 0; j < 16; ++j) { bool c = (j != i1) && (v[j] > h2); h2 = c ? v[j] : h2; i2 = c ? j : i2; }
    bool h2v = true; unsigned taken = 0;
    c0v = NEG_INF; c0c = 0; c1v = NEG_INF; c1c = 0;
#pragma unroll
    for (int r = 0; r < 10; ++r) {
        float M = h1;
        M = fmaxf(M, __shfl_xor(M, 1, 64));
        M = fmaxf(M, __shfl_xor(M, 2, 64));
        M = fmaxf(M, __shfl_xor(M, 4, 64));
        unsigned long long ball = __ballot(h1 == M);
        int base = lane & ~7;
        int srcg = __ffsll((unsigned long long)((ball >> base) & 0xFFull)) - 1;
        int il   = __shfl(i1, base + srcg, 64);
        int col  = srcg * 16 + il;
        if (r < 8) { if (g == r)     { c0v = M; c0c = col; } }
        else       { if (g == r - 8) { c1v = M; c1c = col; } }
        if (g == srcg) {
            taken |= 1u << i1;
            if (h2v) { h1 = h2; i1 = i2; h2v = false; }
            else {
                float bh = -3e38f; int bi = 0;
#pragma unroll
                for (int jx = 0; jx < 16; ++jx) {
                    bool ok = (((taken >> jx) & 1u) == 0u) && (v[jx] > bh);
                    bh = ok ? v[jx] : bh; bi = ok ? jx : bi;
                }
                h1 = bh; i1 = bi;
            }
        }
    }
}

// ---------------------------------------------------------------------------
// K2: att = F F^T, SYMMETRIC 136 upper-triangle pairs — K-loop VERBATIM.
// Epilogue v2: double-buffered stage/select phases (stage pass p+1 while
// selecting pass p), float-compare selection, 3 blocks/CU.
// ---------------------------------------------------------------------------
__global__ __launch_bounds__(256, 3) void att_cand(
        const unsigned short* __restrict__ Fhi, const unsigned short* __restrict__ Flo,
        const int* __restrict__ mask, float* __restrict__ cvO,
        unsigned short* __restrict__ ciO) {
    __shared__ char lds[34816];   // K-loop: 32768; epilogue: 2 x 32x132 f32 = 33792

    const int t = threadIdx.x;
    const int b = blockIdx.x & 7;        // XCD-pinned batch
    int p0 = blockIdx.x >> 3, ti = 0;    // pair 0..135
    while (p0 >= 16 - ti) { p0 -= 16 - ti; ++ti; }
    const int tj = ti + p0;
    const int nBase = ti * 128;
    const int mBase = tj * 128;
    const int w    = t >> 6, lane = t & 63;
    const int q    = lane >> 4, ln = lane & 15;
    const int wn   = (w >> 1) * 64;
    const int wm   = (w & 1) * 64;
    const size_t rowB = (size_t)b * 2048;

    f32x4 acc[4][4] = {};

    for (int kt = 0; kt < 512; kt += 32) {
#pragma unroll
        for (int pp = 0; pp < 4; ++pp) {
            const unsigned short* plane = (pp & 1) ? Flo : Fhi;
            int rbase = (pp < 2) ? nBase : mBase;
#pragma unroll
            for (int r = 0; r < 2; ++r) {
                int chunk = r * 256 + t;
                int row   = chunk >> 2;
                int c     = (chunk & 3) ^ ((row >> 1) & 3);
                const unsigned short* g =
                    plane + ((rowB + rbase + row) * 512 + kt + c * 8);
                char* l = lds + pp * 8192 + chunk * 16;
                __builtin_amdgcn_global_load_lds(
                    (const __attribute__((address_space(1))) void*)g,
                    (__attribute__((address_space(3))) void*)l, 16, 0, 0);
            }
        }
        __syncthreads();

        bf16x8 ah[4], al[4], bh[4], bl[4];
#pragma unroll
        for (int i = 0; i < 4; ++i) {
            int mA = wn + i * 16 + ln;
            int oA = (mA * 4 + (q ^ ((mA >> 1) & 3))) * 16;
            ah[i] = *(const bf16x8*)(lds +     0 + oA);
            al[i] = *(const bf16x8*)(lds +  8192 + oA);
            int mB = wm + i * 16 + ln;
            int oB = (mB * 4 + (q ^ ((mB >> 1) & 3))) * 16;
            bh[i] = *(const bf16x8*)(lds + 16384 + oB);
            bl[i] = *(const bf16x8*)(lds + 24576 + oB);
        }
#pragma unroll
        for (int i = 0; i < 4; ++i)
#pragma unroll
            for (int j = 0; j < 4; ++j) {
                acc[i][j] = __builtin_amdgcn_mfma_f32_16x16x32_bf16(ah[i], bh[j], acc[i][j], 0, 0, 0);
                acc[i][j] = __builtin_amdgcn_mfma_f32_16x16x32_bf16(ah[i], bl[j], acc[i][j], 0, 0, 0);
                acc[i][j] = __builtin_amdgcn_mfma_f32_16x16x32_bf16(al[i], bh[j], acc[i][j], 0, 0, 0);
            }
        __syncthreads();
    }

    // ---------------- candidate-extraction epilogue (dbuf) ----------------
    float* patch = (float*)lds;               // two buffers of [32][132]
    const int* mb = mask + b * 2048;

    int cmj[4];
#pragma unroll
    for (int j = 0; j < 4; ++j) cmj[j] = mb[mBase + wm + j * 16 + ln];
    int rmAll[4][4];
#pragma unroll
    for (int i = 0; i < 4; ++i)
#pragma unroll
        for (int r = 0; r < 4; ++r) rmAll[i][r] = mb[nBase + wn + i * 16 + q * 4 + r];

    const int pr = t >> 3, g = t & 7;         // selection role: row pr, lane g
    const int nPass = (ti != tj) ? 8 : 4;

    auto stageRow = [&](int i, float* buf) {
        int prBase = (w >> 1) * 16;
#pragma unroll
        for (int j = 0; j < 4; ++j)
#pragma unroll
            for (int r = 0; r < 4; ++r) {
                float vv = ((rmAll[i][r] != 0) & (cmj[j] != 0)) ? acc[i][j][r] : NEG_INF;
                buf[(prBase + q * 4 + r) * 132 + wm + j * 16 + ln] = vv;
            }
    };
    auto stageMir = [&](int c2, float* buf) {
        if ((w & 1) == (c2 >> 1)) {
            int jb = (c2 & 1) * 2;
#pragma unroll
            for (int jj = 0; jj < 2; ++jj) {
                int j = jb + jj;
#pragma unroll
                for (int i2 = 0; i2 < 4; ++i2)
#pragma unroll
                    for (int r = 0; r < 4; ++r) {
                        float vv = ((rmAll[i2][r] != 0) & (cmj[j] != 0)) ? acc[i2][j][r] : NEG_INF;
                        buf[(jj * 16 + ln) * 132 + wn + i2 * 16 + q * 4 + r] = vv;
                    }
            }
        }
    };

    stageRow(0, patch);                       // prologue into buf0
    __syncthreads();

#pragma unroll
    for (int p = 0; p < 8; ++p) {
        if (p < nPass) {
            // stage next pass into the other buffer (overlaps with selection)
            if (p + 1 < nPass) {
                float* nbuf = patch + ((p + 1) & 1) * 4224;
                if (p + 1 < 4) stageRow(p + 1, nbuf);
                else           stageMir(p + 1 - 4, nbuf);
            }
            // select current pass from its buffer
            float c0v, c1v; int c0c, c1c;
            const float* prow = patch + (p & 1) * 4224 + pr * 132 + g * 16;
            select10f(prow, lane, c0v, c0c, c1v, c1c);

            int rowG, slot, colbase;
            if (p < 4) {
                rowG = nBase + ((pr >> 4) << 6) + p * 16 + (pr & 15);
                slot = tj; colbase = mBase;
            } else {
                rowG = mBase + (p - 4) * 32 + pr;
                slot = ti; colbase = nBase;
            }
            size_t cb = (((size_t)b * 2048 + rowG) * 16 + slot) * 10;
            cvO[cb + g] = c0v;
            ciO[cb + g] = (unsigned short)(colbase + c0c);
            if (g < 2) {
                cvO[cb + 8 + g] = c1v;
                ciO[cb + 8 + g] = (unsigned short)(colbase + c1c);
            }
            __syncthreads();
        }
    }
}

// ---------------------------------------------------------------------------
// K3: merge 16x10 exact per-tile candidates per row -> global top-10,
// write NEG_INF-filled row + scatter. One wave per row, zero barriers. VERBATIM.
// ---------------------------------------------------------------------------
__global__ __launch_bounds__(256) void topk_merge(
        const float* __restrict__ cv, const unsigned short* __restrict__ ci,
        float* __restrict__ out) {
    __shared__ float patch[4][2048];

    const int t = threadIdx.x, w = t >> 6, lane = t & 63;
    const size_t R = (size_t)blockIdx.x * 4 + w;      // global row 0..16383
    const float* v = cv + R * 160;
    const unsigned short* id = ci + R * 160;

    float v0 = v[lane], v1 = v[lane + 64];
    int   c0 = id[lane], c1 = id[lane + 64];
    float v2 = NEG_INF;  int c2 = 0;
    if (lane < 32) { v2 = v[lane + 128]; c2 = id[lane + 128]; }
    unsigned k0 = fkey(v0), k1 = fkey(v1), k2 = fkey(v2);

    unsigned h1 = k0; int i1 = 0;
    if (k1 > h1) { h1 = k1; i1 = 1; }
    if (k2 > h1) { h1 = k2; i1 = 2; }
    unsigned taken = 0;
    unsigned myk = 0; int mycol = 0;

    for (int r = 0; r < 10; ++r) {
        unsigned M = h1;
#pragma unroll
        for (int off = 1; off < 64; off <<= 1) {
            unsigned o = __shfl_xor(M, off, 64);
            M = (o > M) ? o : M;
        }
        unsigned long long ball = __ballot(h1 == M);
        int src = __ffsll(ball) - 1;
        int csel = (i1 == 0) ? c0 : ((i1 == 1) ? c1 : c2);
        int wcol = __shfl(csel, src, 64);
        if (lane == r) { myk = M; mycol = wcol; }
        if (lane == src) {
            taken |= 1u << i1;
            unsigned bh = 0; int bi = 0;
            if (!(taken & 1u))            { bh = k0; bi = 0; }
            if (!(taken & 2u) && k1 > bh) { bh = k1; bi = 1; }
            if (!(taken & 4u) && k2 > bh) { bh = k2; bi = 2; }
            h1 = bh; i1 = bi;
        }
    }

    float* pw = patch[w];
    float4 ninf4 = make_float4(NEG_INF, NEG_INF, NEG_INF, NEG_INF);
#pragma unroll
    for (int s = 0; s < 8; ++s) ((float4*)pw)[s * 64 + lane] = ninf4;
    if (lane < 10) pw[mycol] = unfkey(myk);
    float* row = out + R * 2048;
#pragma unroll
    for (int s = 0; s < 8; ++s)
        ((float4*)row)[s * 64 + lane] = ((float4*)pw)[s * 64 + lane];
}

// ---------------------------------------------------------------------------
extern "C" void kernel_launch(void* const* d_in, const int* in_sizes, int n_in,
                              void* d_out, int out_size, void* d_ws, size_t ws_size,
                              hipStream_t stream) {
    const float* ctx  = (const float*)d_in[0];   // [8, 2048, 512]
    const float* W    = (const float*)d_in[1];   // [512, 512]
    const int*   mask = (const int*)d_in[2];     // [8, 2048]
    float* out = (float*)d_out;                  // [8, 2048, 2048]

    const size_t CN = (size_t)16384 * 512;
    const size_t WN = (size_t)512 * 512;
    // split planes live in the (still-unwritten) 134 MB output buffer
    unsigned short* C1 = (unsigned short*)d_out;
    unsigned short* C2 = C1 + CN;
    unsigned short* C3 = C2 + CN;
    unsigned short* W1 = C3 + CN;
    unsigned short* W2 = W1 + WN;
    unsigned short* W3 = W2 + WN;                // ends at 51.9 MB
    // Fhi/Flo also in d_out: [51.9 MB, 85.5 MB) < 134 MB, disjoint from planes.
    unsigned short* Fhi = W3 + WN;
    unsigned short* Flo = Fhi + CN;

    float* cv          = (float*)d_ws;                       // [8*2048][16][10] f32
    unsigned short* ci = (unsigned short*)(cv + (size_t)8 * 2048 * 160); // u16 cols

    dim3 blk(256);
    split3_all<<<dim3(2112), blk, 0, stream>>>(ctx, W, C1, C2, C3, W1, W2, W3);
    fc_mfma6<<<dim3(128, 4), blk, 0, stream>>>(C1, C2, C3, W1, W2, W3, Fhi, Flo);
    att_cand<<<dim3(1088), blk, 0, stream>>>(Fhi, Flo, mask, cv, ci);
    topk_merge<<<dim3(4096), blk, 0, stream>>>(cv, ci, out);
}

// Round 3
// 294.364 us; speedup vs baseline: 1.2100x; 1.1815x over previous
//
#include <hip/hip_runtime.h>
#include <hip/hip_bf16.h>

#define NEG_INF -1e20f

typedef __bf16 bf16x8 __attribute__((ext_vector_type(8)));
typedef float  f32x4  __attribute__((ext_vector_type(4)));

__device__ inline unsigned short f2bf(float x) {            // RNE, no NaN inputs
    unsigned u = __float_as_uint(x);
    unsigned r = u + 0x7fffu + ((u >> 16) & 1u);
    return (unsigned short)(r >> 16);
}
__device__ inline float bf2f(unsigned short h) {
    return __uint_as_float((unsigned)h << 16);
}
__device__ inline unsigned fkey(float f) {
    unsigned u = __float_as_uint(f);
    return (u & 0x80000000u) ? ~u : (u | 0x80000000u);
}
__device__ inline float unfkey(unsigned k) {
    unsigned fu = (k & 0x80000000u) ? (k ^ 0x80000000u) : ~k;
    return __uint_as_float(fu);
}

// ---------------------------------------------------------------------------
// K0: split ctx AND W into 3 bf16 planes each, one launch. VERBATIM R0.
// ---------------------------------------------------------------------------
__global__ __launch_bounds__(256) void split3_all(
        const float* __restrict__ ctx, const float* __restrict__ W,
        unsigned short* __restrict__ C1, unsigned short* __restrict__ C2,
        unsigned short* __restrict__ C3, unsigned short* __restrict__ W1,
        unsigned short* __restrict__ W2, unsigned short* __restrict__ W3) {
    const int b = blockIdx.x;
    const int t = threadIdx.x;
    const float* src;
    unsigned short *p1, *p2, *p3;
    int base;
    if (b < 2048) { src = ctx; p1 = C1; p2 = C2; p3 = C3; base = b * 1024; }
    else          { src = W;   p1 = W1; p2 = W2; p3 = W3; base = (b - 2048) * 1024; }
#pragma unroll
    for (int it = 0; it < 4; ++it) {
        int i = base + it * 256 + t;
        float4 v = ((const float4*)src)[i];
        ushort4 a, bb, c;
        float r;
        a.x = f2bf(v.x); r = v.x - bf2f(a.x); bb.x = f2bf(r); c.x = f2bf(r - bf2f(bb.x));
        a.y = f2bf(v.y); r = v.y - bf2f(a.y); bb.y = f2bf(r); c.y = f2bf(r - bf2f(bb.y));
        a.z = f2bf(v.z); r = v.z - bf2f(a.z); bb.z = f2bf(r); c.z = f2bf(r - bf2f(bb.z));
        a.w = f2bf(v.w); r = v.w - bf2f(a.w); bb.w = f2bf(r); c.w = f2bf(r - bf2f(bb.w));
        ((ushort4*)p1)[i] = a;
        ((ushort4*)p2)[i] = bb;
        ((ushort4*)p3)[i] = c;
    }
}

// ---------------------------------------------------------------------------
// K1: ctx_fc = relu(context @ W^T) via 6-term bf16 MFMA, 128x128 tile. VERBATIM R0.
// ---------------------------------------------------------------------------
__global__ __launch_bounds__(256, 2) void fc_mfma6(
        const unsigned short* __restrict__ A1, const unsigned short* __restrict__ A2,
        const unsigned short* __restrict__ A3, const unsigned short* __restrict__ B1,
        const unsigned short* __restrict__ B2, const unsigned short* __restrict__ B3,
        unsigned short* __restrict__ Fhi, unsigned short* __restrict__ Flo) {
    __shared__ char lds[49152];

    const int t     = threadIdx.x;
    const int mBase = blockIdx.x * 128;
    const int hBase = blockIdx.y * 128;
    const int w = t >> 6, lane = t & 63;
    const int q = lane >> 4, ln = lane & 15;
    const int wn = (w >> 1) * 64;
    const int wm = (w & 1) * 64;

    f32x4 acc[4][4] = {};

    for (int kt = 0; kt < 512; kt += 32) {
#pragma unroll
        for (int p = 0; p < 3; ++p) {
            const unsigned short* pl = (p == 0) ? A1 : (p == 1) ? A2 : A3;
#pragma unroll
            for (int rr = 0; rr < 2; ++rr) {
                int chunk = rr * 256 + t;
                int row   = chunk >> 2;
                int c     = (chunk & 3) ^ ((row >> 1) & 3);
                const unsigned short* g = pl + ((size_t)(mBase + row) * 512 + kt + c * 8);
                char* l = lds + p * 8192 + chunk * 16;
                __builtin_amdgcn_global_load_lds(
                    (const __attribute__((address_space(1))) void*)g,
                    (__attribute__((address_space(3))) void*)l, 16, 0, 0);
            }
        }
#pragma unroll
        for (int p = 0; p < 3; ++p) {
            const unsigned short* pl = (p == 0) ? B1 : (p == 1) ? B2 : B3;
#pragma unroll
            for (int rr = 0; rr < 2; ++rr) {
                int chunk = rr * 256 + t;
                int row   = chunk >> 2;
                int c     = (chunk & 3) ^ ((row >> 1) & 3);
                const unsigned short* g = pl + ((size_t)(hBase + row) * 512 + kt + c * 8);
                char* l = lds + 24576 + p * 8192 + chunk * 16;
                __builtin_amdgcn_global_load_lds(
                    (const __attribute__((address_space(1))) void*)g,
                    (__attribute__((address_space(3))) void*)l, 16, 0, 0);
            }
        }
        __syncthreads();

        bf16x8 a1[4], a2[4], a3[4], b1[4], b2[4], b3[4];
#pragma unroll
        for (int i = 0; i < 4; ++i) {
            int mA = wn + i * 16 + ln;
            int oA = (mA * 4 + (q ^ ((mA >> 1) & 3))) * 16;
            a1[i] = *(const bf16x8*)(lds +     0 + oA);
            a2[i] = *(const bf16x8*)(lds +  8192 + oA);
            a3[i] = *(const bf16x8*)(lds + 16384 + oA);
            int mB = wm + i * 16 + ln;
            int oB = (mB * 4 + (q ^ ((mB >> 1) & 3))) * 16;
            b1[i] = *(const bf16x8*)(lds + 24576 + oB);
            b2[i] = *(const bf16x8*)(lds + 32768 + oB);
            b3[i] = *(const bf16x8*)(lds + 40960 + oB);
        }
#pragma unroll
        for (int i = 0; i < 4; ++i)
#pragma unroll
            for (int j = 0; j < 4; ++j) {
                acc[i][j] = __builtin_amdgcn_mfma_f32_16x16x32_bf16(a1[i], b1[j], acc[i][j], 0, 0, 0);
                acc[i][j] = __builtin_amdgcn_mfma_f32_16x16x32_bf16(a1[i], b2[j], acc[i][j], 0, 0, 0);
                acc[i][j] = __builtin_amdgcn_mfma_f32_16x16x32_bf16(a2[i], b1[j], acc[i][j], 0, 0, 0);
                acc[i][j] = __builtin_amdgcn_mfma_f32_16x16x32_bf16(a2[i], b2[j], acc[i][j], 0, 0, 0);
                acc[i][j] = __builtin_amdgcn_mfma_f32_16x16x32_bf16(a1[i], b3[j], acc[i][j], 0, 0, 0);
                acc[i][j] = __builtin_amdgcn_mfma_f32_16x16x32_bf16(a3[i], b1[j], acc[i][j], 0, 0, 0);
            }
        __syncthreads();
    }

    unsigned* tb = (unsigned*)(lds + w * 4352);
    const int rg = lane >> 4;
    const int c4 = lane & 15;
#pragma unroll
    for (int i = 0; i < 4; ++i) {
#pragma unroll
        for (int j = 0; j < 4; ++j)
#pragma unroll
            for (int r = 0; r < 4; ++r) {
                float v = fmaxf(acc[i][j][r], 0.f);
                unsigned short hi = f2bf(v);
                unsigned short lo = f2bf(v - bf2f(hi));
                tb[(q * 4 + r) * 68 + j * 16 + ln] =
                    (unsigned)hi | ((unsigned)lo << 16);
            }
#pragma unroll
        for (int it = 0; it < 4; ++it) {
            int row = it * 4 + rg;
            uint4 pk = *(const uint4*)&tb[row * 68 + c4 * 4];
            ushort4 h, l;
            h.x = (unsigned short)pk.x; l.x = (unsigned short)(pk.x >> 16);
            h.y = (unsigned short)pk.y; l.y = (unsigned short)(pk.y >> 16);
            h.z = (unsigned short)pk.z; l.z = (unsigned short)(pk.z >> 16);
            h.w = (unsigned short)pk.w; l.w = (unsigned short)(pk.w >> 16);
            size_t off = (size_t)(mBase + wn + i * 16 + row) * 512 + hBase + wm + c4 * 4;
            *(ushort4*)(Fhi + off) = h;
            *(ushort4*)(Flo + off) = l;
        }
    }
}

// ---------------------------------------------------------------------------
// K2: att = F F^T via bf16x3 MFMA — SYMMETRIC (136 upper-triangle pairs),
// full-matrix write (R0 VERBATIM K-loop + epilogue) PLUS per-row per-64-col-
// half maxima emitted to cv2[b*2048+row][32] (exact lower-bound candidates
// for K3's threshold filter). 3 blocks/CU.
// ---------------------------------------------------------------------------
__global__ __launch_bounds__(256, 3) void att_sym_cand(
        const unsigned short* __restrict__ Fhi, const unsigned short* __restrict__ Flo,
        const int* __restrict__ mask, float* __restrict__ out,
        float* __restrict__ cv2) {
    __shared__ char lds[32768];

    const int t = threadIdx.x;
    const int b = blockIdx.x & 7;        // XCD-pinned batch
    int p = blockIdx.x >> 3, ti = 0;     // pair 0..135
    while (p >= 16 - ti) { p -= 16 - ti; ++ti; }
    const int tj = ti + p;
    const int nBase = ti * 128;
    const int mBase = tj * 128;
    const int w    = t >> 6, lane = t & 63;
    const int q    = lane >> 4, ln = lane & 15;
    const int wn   = (w >> 1) * 64;
    const int wm   = (w & 1) * 64;
    const size_t rowB = (size_t)b * 2048;

    f32x4 acc[4][4] = {};

    for (int kt = 0; kt < 512; kt += 32) {
#pragma unroll
        for (int pp = 0; pp < 4; ++pp) {
            const unsigned short* plane = (pp & 1) ? Flo : Fhi;
            int rbase = (pp < 2) ? nBase : mBase;
#pragma unroll
            for (int r = 0; r < 2; ++r) {
                int chunk = r * 256 + t;
                int row   = chunk >> 2;
                int c     = (chunk & 3) ^ ((row >> 1) & 3);
                const unsigned short* g =
                    plane + ((rowB + rbase + row) * 512 + kt + c * 8);
                char* l = lds + pp * 8192 + chunk * 16;
                __builtin_amdgcn_global_load_lds(
                    (const __attribute__((address_space(1))) void*)g,
                    (__attribute__((address_space(3))) void*)l, 16, 0, 0);
            }
        }
        __syncthreads();

        bf16x8 ah[4], al[4], bh[4], bl[4];
#pragma unroll
        for (int i = 0; i < 4; ++i) {
            int mA = wn + i * 16 + ln;
            int oA = (mA * 4 + (q ^ ((mA >> 1) & 3))) * 16;
            ah[i] = *(const bf16x8*)(lds +     0 + oA);
            al[i] = *(const bf16x8*)(lds +  8192 + oA);
            int mB = wm + i * 16 + ln;
            int oB = (mB * 4 + (q ^ ((mB >> 1) & 3))) * 16;
            bh[i] = *(const bf16x8*)(lds + 16384 + oB);
            bl[i] = *(const bf16x8*)(lds + 24576 + oB);
        }
#pragma unroll
        for (int i = 0; i < 4; ++i)
#pragma unroll
            for (int j = 0; j < 4; ++j) {
                acc[i][j] = __builtin_amdgcn_mfma_f32_16x16x32_bf16(ah[i], bh[j], acc[i][j], 0, 0, 0);
                acc[i][j] = __builtin_amdgcn_mfma_f32_16x16x32_bf16(ah[i], bl[j], acc[i][j], 0, 0, 0);
                acc[i][j] = __builtin_amdgcn_mfma_f32_16x16x32_bf16(al[i], bh[j], acc[i][j], 0, 0, 0);
            }
        __syncthreads();
    }

    const int* mb = mask + b * 2048;
    float* outB = out + (size_t)b * 2048 * 2048;
    int cmj[4];
#pragma unroll
    for (int j = 0; j < 4; ++j) cmj[j] = mb[mBase + wm + j * 16 + ln];
    int rmAll[4][4];
#pragma unroll
    for (int i = 0; i < 4; ++i)
#pragma unroll
        for (int r = 0; r < 4; ++r) rmAll[i][r] = mb[nBase + wn + i * 16 + q * 4 + r];

    float* tb = (float*)(lds + w * 4352);
    const int rg = lane >> 4;
    const int c4 = lane & 15;
    const bool mirror = (ti != tj);
#pragma unroll
    for (int i = 0; i < 4; ++i) {
        int n0 = nBase + wn + i * 16;
        // --- candidate: per-row max over this wave's 64-col half ---
#pragma unroll
        for (int r = 0; r < 4; ++r) {
            float m4 = NEG_INF;
#pragma unroll
            for (int j = 0; j < 4; ++j) {
                float v = ((rmAll[i][r] != 0) & (cmj[j] != 0)) ? acc[i][j][r] : NEG_INF;
                m4 = fmaxf(m4, v);
            }
            m4 = fmaxf(m4, __shfl_xor(m4, 1, 64));
            m4 = fmaxf(m4, __shfl_xor(m4, 2, 64));
            m4 = fmaxf(m4, __shfl_xor(m4, 4, 64));
            m4 = fmaxf(m4, __shfl_xor(m4, 8, 64));
            if (ln == 0)
                cv2[(rowB + n0 + q * 4 + r) * 32 + tj * 2 + (w & 1)] = m4;
        }
        // --- matrix write (R0 verbatim) ---
#pragma unroll
        for (int j = 0; j < 4; ++j)
#pragma unroll
            for (int r = 0; r < 4; ++r) {
                float v = ((rmAll[i][r] != 0) & (cmj[j] != 0)) ? acc[i][j][r] : NEG_INF;
                tb[(q * 4 + r) * 68 + j * 16 + ln] = v;
            }
#pragma unroll
        for (int it = 0; it < 4; ++it) {
            int row = it * 4 + rg;
            float4 vv = *(const float4*)&tb[row * 68 + c4 * 4];
            *(float4*)(outB + (size_t)(n0 + row) * 2048 + mBase + wm + c4 * 4) = vv;
        }
        if (mirror) {
#pragma unroll
            for (int ps = 0; ps < 4; ++ps) {
                float4 mv;
                mv.x = tb[(ps * 4 + 0) * 68 + lane];
                mv.y = tb[(ps * 4 + 1) * 68 + lane];
                mv.z = tb[(ps * 4 + 2) * 68 + lane];
                mv.w = tb[(ps * 4 + 3) * 68 + lane];
                *(float4*)(outB + (size_t)(mBase + wm + lane) * 2048 + n0 + ps * 4) = mv;
            }
        }
    }
    // --- mirror candidates: per mirror-row max over this wave's wn half ---
    if (mirror) {
#pragma unroll
        for (int j = 0; j < 4; ++j) {
            float m16 = NEG_INF;
#pragma unroll
            for (int i2 = 0; i2 < 4; ++i2)
#pragma unroll
                for (int r = 0; r < 4; ++r) {
                    float v = ((rmAll[i2][r] != 0) & (cmj[j] != 0)) ? acc[i2][j][r] : NEG_INF;
                    m16 = fmaxf(m16, v);
                }
            m16 = fmaxf(m16, __shfl_xor(m16, 16, 64));
            m16 = fmaxf(m16, __shfl_xor(m16, 32, 64));
            if (q == 0)
                cv2[(rowB + mBase + wm + j * 16 + ln) * 32 + ti * 2 + (w >> 1)] = m16;
        }
    }
}

// ---------------------------------------------------------------------------
// K3: threshold-filtered per-row top-10. One wave per row.
// L = 10th-largest of the row's 32 half-maxima (valid lower bound on the true
// 10th value). Halves with max < L are not fetched (their lanes' addresses
// are redirected to a selected half; dup loads are L1 broadcasts). Survivors
// (v >= L, typically ~12) are ballot-compacted to LDS and ranked by broadcast
// reads -- no serial extraction rounds. Fallback: verbatim R13 extraction if
// survivors > 64 (degenerate/masked rows).
// ---------------------------------------------------------------------------
__global__ __launch_bounds__(256) void topk_filter(
        const float* __restrict__ cv2, float* __restrict__ att) {
    __shared__ float  patch[4][2048];
    __shared__ float2 surv[4][64];

    const int t = threadIdx.x, w = t >> 6, lane = t & 63;
    const size_t R = (size_t)blockIdx.x * 4 + w;      // global row 0..16383
    float* row = att + R * 2048;

    // ---- L = 10th-largest of 32 half-maxima (rank via readlane broadcast) ----
    float cnd = (lane < 32) ? cv2[R * 32 + lane] : NEG_INF;
    int rk = 0;
#pragma unroll
    for (int j = 0; j < 32; ++j) {
        float vj = __shfl(cnd, j, 64);
        rk += ((vj > cnd) || (vj == cnd && j < lane)) ? 1 : 0;
    }
    unsigned long long bl = __ballot((lane < 32) && (rk == 9));
    float L = __shfl(cnd, __ffsll(bl) - 1, 64);
    unsigned long long hsel = __ballot((lane < 32) && (cnd >= L));
    int hFirst = __ffsll(hsel) - 1;

    // ---- fetch: selected halves only (others redirected = L1 dup reads) ----
    const bool sel = (hsel >> (lane >> 1)) & 1ull;
    const float* src = row + (sel ? lane * 32 : hFirst * 64 + (lane & 1) * 32);
    float4 v4[8];
#pragma unroll
    for (int s = 0; s < 8; ++s) v4[s] = *(const float4*)(src + s * 4);

    // ---- ballot-compact survivors (v >= L) ----
    int nsurv = 0;
    const unsigned long long lmask = (1ull << lane) - 1;
    auto push = [&](float val, int col) {
        bool pr = sel && (val >= L);
        unsigned long long pb = __ballot(pr);
        if (pr) {
            int idx = nsurv + (int)__popcll(pb & lmask);
            if (idx < 64) surv[w][idx] = make_float2(val, __int_as_float(col));
        }
        nsurv += (int)__popcll(pb);
    };
#pragma unroll
    for (int s = 0; s < 8; ++s) {
        int cb = lane * 32 + s * 4;
        push(v4[s].x, cb + 0);
        push(v4[s].y, cb + 1);
        push(v4[s].z, cb + 2);
        push(v4[s].w, cb + 3);
    }

    bool win = false; float myv = NEG_INF; int mycol = 0;
    if (nsurv <= 64) {
        // ---- rank-select top-10 among survivors (value desc, col asc) ----
        float sv = NEG_INF; int sc = 0x7fffffff;
        if (lane < nsurv) {
            float2 s2 = surv[w][lane];
            sv = s2.x; sc = __float_as_int(s2.y);
        }
        int r2 = 0;
        for (int j = 0; j < nsurv; ++j) {
            float2 sj = surv[w][j];            // LDS broadcast read
            int cj = __float_as_int(sj.y);
            r2 += ((sj.x > sv) || (sj.x == sv && cj < sc)) ? 1 : 0;
        }
        win = (lane < nsurv) && (r2 < 10);
        myv = sv; mycol = win ? sc : 0;
    } else {
        // ---- fallback: verbatim R13 full extraction (reload full row) ----
        unsigned key[32];
#pragma unroll
        for (int s = 0; s < 8; ++s) {
            float4 v = *(const float4*)(row + lane * 32 + s * 4);
            key[s * 4 + 0] = fkey(v.x);
            key[s * 4 + 1] = fkey(v.y);
            key[s * 4 + 2] = fkey(v.z);
            key[s * 4 + 3] = fkey(v.w);
        }
        unsigned h1 = key[0]; int i1 = 0;
#pragma unroll
        for (int j = 1; j < 32; ++j)
            if (key[j] > h1) { h1 = key[j]; i1 = j; }
        unsigned h2 = 0; int i2 = 0;
#pragma unroll
        for (int j = 0; j < 32; ++j) {
            bool ok = (j != i1) && (key[j] > h2);
            h2 = ok ? key[j] : h2;
            i2 = ok ? j : i2;
        }
        bool h2valid = true;
        unsigned taken = 0;
        unsigned myk = 0; int myidx = 0;
        for (int r = 0; r < 10; ++r) {
            unsigned M = h1;
#pragma unroll
            for (int off = 1; off < 64; off <<= 1) {
                unsigned o = __shfl_xor(M, off, 64);
                M = (o > M) ? o : M;
            }
            unsigned long long ball = __ballot(h1 == M);
            int srcb = __ffsll(ball) - 1;
            int wloc = __shfl(i1, srcb, 64);
            if (lane == r) { myk = M; myidx = srcb * 32 + wloc; }
            if (lane == srcb) {
                taken |= 1u << i1;
                if (h2valid) { h1 = h2; i1 = i2; h2valid = false; }
                else {
                    unsigned bh = 0; int bi = 0;
#pragma unroll
                    for (int j = 0; j < 32; ++j) {
                        bool ok = (((taken >> j) & 1u) == 0u) && (key[j] > bh);
                        bh = ok ? key[j] : bh;
                        bi = ok ? j : bi;
                    }
                    h1 = bh; i1 = bi;
                }
            }
        }
        win = (lane < 10);
        myv = unfkey(myk); mycol = win ? myidx : 0;
    }

    // ---- unified write: NEG_INF patch + scatter winners + copy out ----
    float* pw = patch[w];
    float4 ninf4 = make_float4(NEG_INF, NEG_INF, NEG_INF, NEG_INF);
#pragma unroll
    for (int s = 0; s < 8; ++s) ((float4*)pw)[s * 64 + lane] = ninf4;
    if (win) pw[mycol] = myv;
#pragma unroll
    for (int s = 0; s < 8; ++s)
        ((float4*)row)[s * 64 + lane] = ((float4*)pw)[s * 64 + lane];
}

// ---------------------------------------------------------------------------
extern "C" void kernel_launch(void* const* d_in, const int* in_sizes, int n_in,
                              void* d_out, int out_size, void* d_ws, size_t ws_size,
                              hipStream_t stream) {
    const float* ctx  = (const float*)d_in[0];   // [8, 2048, 512]
    const float* W    = (const float*)d_in[1];   // [512, 512]
    const int*   mask = (const int*)d_in[2];     // [8, 2048]
    float* out = (float*)d_out;                  // [8, 2048, 2048]

    const size_t CN = (size_t)16384 * 512;
    const size_t WN = (size_t)512 * 512;
    // split planes live in the (still-unwritten) 134 MB output buffer (R0 layout);
    // att overwrites them with the matrix AFTER fc has consumed them.
    unsigned short* C1 = (unsigned short*)d_out;
    unsigned short* C2 = C1 + CN;
    unsigned short* C3 = C2 + CN;
    unsigned short* W1 = C3 + CN;
    unsigned short* W2 = W1 + WN;
    unsigned short* W3 = W2 + WN;                // ends at 51.9 MB < 134 MB

    // workspace: cv2 (2 MB) + Fhi/Flo (33.5 MB)
    float* cv2 = (float*)d_ws;                              // [16384][32] f32
    unsigned short* Fhi = (unsigned short*)(cv2 + (size_t)16384 * 32);
    unsigned short* Flo = Fhi + CN;

    dim3 blk(256);
    split3_all<<<dim3(2112), blk, 0, stream>>>(ctx, W, C1, C2, C3, W1, W2, W3);
    fc_mfma6<<<dim3(128, 4), blk, 0, stream>>>(C1, C2, C3, W1, W2, W3, Fhi, Flo);
    att_sym_cand<<<dim3(1088), blk, 0, stream>>>(Fhi, Flo, mask, out, cv2);
    topk_filter<<<dim3(4096), blk, 0, stream>>>(cv2, out);
}